// Round 4
// baseline (494.610 us; speedup 1.0000x reference)
//
#include <hip/hip_runtime.h>

// Problem constants (from reference): T=1024, B=32, D=768, L=48
#define T_ 1024
#define B_ 32
#define D_ 768
#define L_ 48
#define TB_ (T_ * B_)   // 32768 rows of the emissions GEMM

typedef __attribute__((ext_vector_type(4))) float f32x4;

// ---------------------------------------------------------------------------
// Kernel A: E = exp(feats @ W + b)   (fp32, M=32768 N=48 K=768)  — unchanged
// from the 446.8 µs harness-verified version.
// block = 256 threads (4 waves), tile = 128 rows x 48 cols, K-chunks of 64.
// feats staged via global_load_lds (width 16) into an UNPADDED 128x64 LDS
// buffer with XOR swizzle; W staged through VGPRs into wbuf padded 68.
// ---------------------------------------------------------------------------
__global__ __launch_bounds__(256) void emis_gemm(
    const float* __restrict__ feats, const float* __restrict__ W,
    const float* __restrict__ bias, float* __restrict__ E) {
  __shared__ float fbuf[128 * 64];   // row-major, 16 chunks of 16B per row
  __shared__ float wbuf[48 * 68];    // wbuf[j][ko], padded
  const int tid = threadIdx.x;
  const int wv = tid >> 6;           // wave id 0..3
  const int lane = tid & 63;
  const int cg = tid & 7;            // col group -> cols c0..c0+5
  const int rg = tid >> 3;           // row group 0..31 -> rows rg+32i
  const int c0 = cg * 6;
  const int rowbase = blockIdx.x * 128;
  const int r7 = rg & 7;

  float acc[4][6];
#pragma unroll
  for (int i = 0; i < 4; i++)
#pragma unroll
    for (int c = 0; c < 6; c++) acc[i][c] = 0.f;

  for (int kc = 0; kc < D_; kc += 64) {
    __syncthreads();  // previous chunk's reads complete before overwrite

#pragma unroll
    for (int inst = 0; inst < 8; inst++) {
      const int rowstart = wv * 32 + inst * 4;
      const int r = rowstart + (lane >> 4);
      const int slot = lane & 15;
      const int gch = slot ^ (r & 7);
      const float* g = feats + (size_t)(rowbase + r) * D_ + kc + gch * 4;
      float* l = fbuf + rowstart * 64;  // wave-uniform base; +lane*16B implied
      __builtin_amdgcn_global_load_lds(
          (const __attribute__((address_space(1))) uint32_t*)g,
          (__attribute__((address_space(3))) uint32_t*)l, 16, 0, 0);
    }

#pragma unroll
    for (int i = 0; i < 12; i++) {
      const int idx = tid + i * 256;  // 0..3071
      const int ko = idx / 48;
      const int j = idx - ko * 48;
      wbuf[j * 68 + ko] = W[(kc + ko) * L_ + j];
    }

    __syncthreads();  // drains vmcnt (global_load_lds) + lgkm (ds_write)

#pragma unroll 4
    for (int k4 = 0; k4 < 16; k4++) {
      float4 fv[4];
      float4 wv4[6];
      const int sch = (k4 ^ r7) << 2;  // swizzled chunk offset (floats)
#pragma unroll
      for (int i = 0; i < 4; i++)
        fv[i] = *(const float4*)(fbuf + (rg + 32 * i) * 64 + sch);
#pragma unroll
      for (int c = 0; c < 6; c++)
        wv4[c] = *(const float4*)(wbuf + (c0 + c) * 68 + k4 * 4);
#pragma unroll
      for (int i = 0; i < 4; i++) {
#pragma unroll
        for (int c = 0; c < 6; c++) {
          acc[i][c] = fmaf(fv[i].x, wv4[c].x, acc[i][c]);
          acc[i][c] = fmaf(fv[i].y, wv4[c].y, acc[i][c]);
          acc[i][c] = fmaf(fv[i].z, wv4[c].z, acc[i][c]);
          acc[i][c] = fmaf(fv[i].w, wv4[c].w, acc[i][c]);
        }
      }
    }
  }

#pragma unroll
  for (int i = 0; i < 4; i++) {
    float* dst = E + (size_t)(rowbase + rg + 32 * i) * L_ + c0;
#pragma unroll
    for (int c = 0; c < 6; c += 2) {
      float2 v;
      v.x = __expf(acc[i][c + 0] + bias[c0 + c + 0]);
      v.y = __expf(acc[i][c + 1] + bias[c0 + c + 1]);
      *(float2*)(dst + c) = v;
    }
  }
}

// ---------------------------------------------------------------------------
// Kernel B: one block (128 threads) per batch element; wave 0 runs the
// unconstrained forward scan, wave 1 the constrained partial scan.  The two
// waves are fully independent during the scan (no barriers) — each runs a
// scaled-probability-space recurrence with:
//   - state broadcast via LDS: lane j publishes a[j] (1 ds_write_b32,
//     stride-1 = conflict-free), all lanes re-read the full 48-float state
//     as 12 broadcast ds_read_b128 (same-address = conflict-free),
//     double-buffered by step parity so reads never wait on anti-deps.
//   - matvec: 48 fmaf in 4 independent chains per lane (lane j owns row j
//     of exp(trans), constrained-masked on wave 1).
//   - deferred rescale: every 8th step computes the wave-max m of the new
//     state but does NOT touch it; the scale 1/m is folded into the NEXT
//     step's emission multiply (pend), keeping the 6-level shfl-max +
//     __logf + rcp chain in the latency shadow of the next step's reads.
//     logacc accumulates log(m); readout adds log(pend) to exactly cancel
//     an unconsumed rescale if the scan ends on a rescale step.
//     Growth bound: worst-case ~1000x/step -> <=1e27 over <=9 unscaled
//     steps, safely below fp32 max (interval 16 would risk overflow).
//   - only wave 1 loads tags; emissions prefetched 8 steps ahead.
// Final: each wave's logZ -> LDS, one barrier, out[b] = logZ_fwd - logZ_par
// (no atomics, no memset dispatch).
// Parity invariants: state(t=0) lands in parity 0; step i reads parity i&1,
// writes parity (i+1)&1; main loop body is 8 steps so it exits with the
// last write in parity 0, matching the tail restarting at i=0.  Tail steps
// execute contiguously from i=0 (skip predicate monotone in i).
// ---------------------------------------------------------------------------
__global__ __launch_bounds__(128) void crf_scan(
    const float* __restrict__ E, const int* __restrict__ tags,
    const int* __restrict__ lens, const float* __restrict__ begin,
    const float* __restrict__ trans, const float* __restrict__ endt,
    const int* __restrict__ bc, const int* __restrict__ ec,
    const int* __restrict__ tc, float* __restrict__ out) {
  __shared__ __align__(16) float sbuf[2][2][64];  // [wave][parity][slot]
  __shared__ float lzbuf[2];
  const int b = blockIdx.x;
  const int wv = threadIdx.x >> 6;   // 0 = fwd, 1 = constrained partial
  const int lane = threadIdx.x & 63;
  const bool act = lane < L_;
  const bool par = (wv == 1);
  const int len = lens[b];            // in [512, 1024]
  const int stride = B_ * L_;
  const int base = b * L_ + (act ? lane : 0);  // clamped for lanes 48..63

  // Transition row of this wave's scan: P[k] = exp(trans[lane][k]),
  // zero for inactive lanes; additionally constraint-masked on wave 1.
  float P[L_];
#pragma unroll
  for (int k = 0; k < L_; k++) P[k] = 0.f;
  if (act) {
#pragma unroll
    for (int k = 0; k < L_; k++) {
      float v = __expf(trans[lane * L_ + k]);
      if (par && tc[lane * L_ + k]) v = 0.f;
      P[k] = v;
    }
  }

  // init: a0 = E[0]*exp(begin); wave 1 additionally masked by bc/tags[0]
  float a = 0.f;
  if (act) {
    a = E[base] * __expf(begin[lane]);
    if (par && (bc[lane] || tags[base])) a = 0.f;
  }
  float logacc = 0.f;
  float pend = 1.f;  // deferred 1/m scale, consumed by next step's emission

  sbuf[wv][0][lane] = a;  // state(t=0) -> buffer parity 0

  auto step = [&](int i, float ev, int tg, bool resc) {
    // evp is ready before the reads return (pend known at step entry), so
    // the final multiply's operand computes in the LDS-latency shadow.
    const float evp = ev * pend;
    pend = 1.f;
    // broadcast reads: all lanes read the same 12 addresses -> conflict-free
    const f32x4* src = (const f32x4*)sbuf[wv][i & 1];
    float s0 = 0.f, s1 = 0.f, s2 = 0.f, s3 = 0.f;
#pragma unroll
    for (int c = 0; c < 12; c++) {
      const f32x4 q = src[c];
      s0 = fmaf(q.x, P[4 * c + 0], s0);
      s1 = fmaf(q.y, P[4 * c + 1], s1);
      s2 = fmaf(q.z, P[4 * c + 2], s2);
      s3 = fmaf(q.w, P[4 * c + 3], s3);
    }
    float u = ((s0 + s1) + (s2 + s3)) * evp;
    if (tg) u = 0.f;  // tg is always 0 on wave 0
    a = u;
    // publish ASAP so the next step's reads issue before the max chain
    sbuf[wv][(i + 1) & 1][lane] = u;
    if (resc) {
      float m = u;
#pragma unroll
      for (int off = 32; off; off >>= 1) m = fmaxf(m, __shfl_xor(m, off, 64));
      m = fmaxf(m, 1e-30f);
      logacc += __logf(m);
      pend = 1.f / m;  // applied inside next step's emission multiply
    }
  };

  // preload emissions/tags for t = 1..8 (len >= 512 so always valid)
  float e8[8];
  int tg8[8];
#pragma unroll
  for (int i = 0; i < 8; i++) {
    e8[i] = E[(size_t)(1 + i) * stride + base];
    tg8[i] = par ? tags[(size_t)(1 + i) * stride + base] : 0;
  }

  int t = 1;  // t stays == 1 (mod 8); rescale lands at unrolled i == 7
  for (; t + 8 <= len; t += 8) {
    float p8[8];
    int q8[8];
#pragma unroll
    for (int i = 0; i < 8; i++) {
      int tt = t + 8 + i;
      tt = (tt < len) ? tt : (len - 1);
      p8[i] = E[(size_t)tt * stride + base];
      q8[i] = par ? tags[(size_t)tt * stride + base] : 0;
    }
#pragma unroll
    for (int i = 0; i < 8; i++) step(i, e8[i], tg8[i], i == 7);
#pragma unroll
    for (int i = 0; i < 8; i++) { e8[i] = p8[i]; tg8[i] = q8[i]; }
  }
  // tail: at most 7 steps; e8 already holds times t..t+7 (clamped), and the
  // main loop's last write landed in parity 0, matching i restarting at 0
#pragma unroll
  for (int i = 0; i < 8; i++) {
    if (t + i < len) step(i, e8[i], tg8[i], false);
  }

  // readout: logZ = logacc + log(pend) + log(sum_j a[j]*exp(end[j]))
  float z = 0.f;
  if (act) {
    float ez = __expf(endt[lane]);
    if (par && ec[lane]) ez = 0.f;
    z = a * ez;
  }
#pragma unroll
  for (int off = 32; off; off >>= 1) z += __shfl_xor(z, off, 64);
  if (lane == 0) lzbuf[wv] = logacc + __logf(pend) + __logf(z);
  __syncthreads();
  if (threadIdx.x == 0) out[b] = lzbuf[0] - lzbuf[1];
}

// ---------------------------------------------------------------------------
extern "C" void kernel_launch(void* const* d_in, const int* in_sizes, int n_in,
                              void* d_out, int out_size, void* d_ws,
                              size_t ws_size, hipStream_t stream) {
  (void)in_sizes; (void)n_in; (void)out_size; (void)ws_size;
  const float* feats = (const float*)d_in[0];
  const int* tags = (const int*)d_in[1];
  const int* lens = (const int*)d_in[2];
  const float* W = (const float*)d_in[3];
  const float* bias = (const float*)d_in[4];
  const float* begin = (const float*)d_in[5];
  const float* trans = (const float*)d_in[6];
  const float* endt = (const float*)d_in[7];
  const int* bc = (const int*)d_in[8];
  const int* ec = (const int*)d_in[9];
  const int* tc = (const int*)d_in[10];

  float* E = (float*)d_ws;  // T*B*L floats = 6 MB scratch, exp(emissions)
  float* out = (float*)d_out;

  emis_gemm<<<dim3(TB_ / 128), dim3(256), 0, stream>>>(feats, W, bias, E);
  crf_scan<<<dim3(B_), dim3(128), 0, stream>>>(E, tags, lens, begin, trans,
                                               endt, bc, ec, tc, out);
}

// Round 5
// 446.715 us; speedup vs baseline: 1.1072x; 1.1072x over previous
//
#include <hip/hip_runtime.h>

// Problem constants (from reference): T=1024, B=32, D=768, L=48
#define T_ 1024
#define B_ 32
#define D_ 768
#define L_ 48
#define TB_ (T_ * B_)   // 32768 rows of the emissions GEMM

typedef __attribute__((ext_vector_type(4))) float f32x4;

// ---------------------------------------------------------------------------
// Kernel A: E = exp(feats @ W + b)   (fp32, M=32768 N=48 K=768)
// NOW DOUBLE-BUFFERED (2-phase): per K-chunk, issue next chunk's
// global_load_lds + W register-loads right AFTER the barrier, compute the
// current chunk (3072 cyc of FMAs hides the ~1000 cyc load latency), then
// ds_write the W regs (vmcnt(8) wait — feats stay in flight).  One barrier
// per chunk instead of two, and the vmcnt(0)-at-barrier drain now waits on
// loads that are ~3000 cycles old -> ~free.
// block = 256 threads (4 waves), tile = 128 rows x 48 cols, K-chunks of 64.
// LDS: fbuf 2x32KB + wbuf 2x13KB = 90 KiB -> 1 block/CU (grid = 256 = #CUs).
// ---------------------------------------------------------------------------
__global__ __launch_bounds__(256, 1) void emis_gemm(
    const float* __restrict__ feats, const float* __restrict__ W,
    const float* __restrict__ bias, float* __restrict__ E) {
  __shared__ float fbuf[2][128 * 64];  // row-major, XOR-swizzled chunks
  __shared__ float wbuf[2][48 * 68];   // wbuf[j][ko], padded
  const int tid = threadIdx.x;
  const int wv = tid >> 6;           // wave id 0..3
  const int lane = tid & 63;
  const int cg = tid & 7;            // col group -> cols c0..c0+5
  const int rg = tid >> 3;           // row group 0..31 -> rows rg+32i
  const int c0 = cg * 6;
  const int rowbase = blockIdx.x * 128;
  const int r7 = rg & 7;
  const int r_in = lane >> 4;        // 0..3 row-within-gload_lds
  const int slot = lane & 15;

  // per-thread W staging geometry (constant across chunks):
  // flat idx = tid + i*256 = ko*48 + j  ->  global addr = W + kc*48 + idx
  int woff[12];
#pragma unroll
  for (int i = 0; i < 12; i++) {
    const int idx = tid + i * 256;
    const int ko = idx / 48;
    const int j = idx - ko * 48;
    woff[i] = j * 68 + ko;
  }

  float acc[4][6];
#pragma unroll
  for (int i = 0; i < 4; i++)
#pragma unroll
    for (int c = 0; c < 6; c++) acc[i][c] = 0.f;

  float wr[12];

  // ---- prologue: stage chunk 0 into buffer 0 ----
  {
#pragma unroll
    for (int i = 0; i < 12; i++) wr[i] = W[tid + i * 256];  // kc = 0
#pragma unroll
    for (int inst = 0; inst < 8; inst++) {
      const int rowstart = wv * 32 + inst * 4;
      const int r = rowstart + r_in;
      const int gch = slot ^ (r & 7);
      const float* g = feats + (size_t)(rowbase + r) * D_ + gch * 4;
      float* l = &fbuf[0][rowstart * 64];  // wave-uniform base
      __builtin_amdgcn_global_load_lds(
          (const __attribute__((address_space(1))) uint32_t*)g,
          (__attribute__((address_space(3))) uint32_t*)l, 16, 0, 0);
    }
#pragma unroll
    for (int i = 0; i < 12; i++) wbuf[0][woff[i]] = wr[i];
  }

  for (int c = 0; c < 12; c++) {
    const int cur = c & 1;
    __syncthreads();  // fbuf/wbuf[cur] ready (their loads are ~3000cy old)

    if (c < 11) {  // issue next chunk's loads; they fly under the compute
      const int kc2 = (c + 1) * 64;
#pragma unroll
      for (int i = 0; i < 12; i++) wr[i] = W[kc2 * L_ + tid + i * 256];
#pragma unroll
      for (int inst = 0; inst < 8; inst++) {
        const int rowstart = wv * 32 + inst * 4;
        const int r = rowstart + r_in;
        const int gch = slot ^ (r & 7);
        const float* g = feats + (size_t)(rowbase + r) * D_ + kc2 + gch * 4;
        float* l = &fbuf[cur ^ 1][rowstart * 64];
        __builtin_amdgcn_global_load_lds(
            (const __attribute__((address_space(1))) uint32_t*)g,
            (__attribute__((address_space(3))) uint32_t*)l, 16, 0, 0);
      }
    }

    const float* fb = fbuf[cur];
    const float* wb = wbuf[cur];
#pragma unroll 4
    for (int k4 = 0; k4 < 16; k4++) {
      float4 fv[4];
      float4 wv4[6];
      const int sch = (k4 ^ r7) << 2;  // swizzled chunk offset (floats)
#pragma unroll
      for (int i = 0; i < 4; i++)
        fv[i] = *(const float4*)(fb + (rg + 32 * i) * 64 + sch);
#pragma unroll
      for (int cc = 0; cc < 6; cc++)
        wv4[cc] = *(const float4*)(wb + (c0 + cc) * 68 + k4 * 4);
#pragma unroll
      for (int i = 0; i < 4; i++) {
#pragma unroll
        for (int cc = 0; cc < 6; cc++) {
          acc[i][cc] = fmaf(fv[i].x, wv4[cc].x, acc[i][cc]);
          acc[i][cc] = fmaf(fv[i].y, wv4[cc].y, acc[i][cc]);
          acc[i][cc] = fmaf(fv[i].z, wv4[cc].z, acc[i][cc]);
          acc[i][cc] = fmaf(fv[i].w, wv4[cc].w, acc[i][cc]);
        }
      }
    }

    if (c < 11) {  // W regs -> next wbuf; vmcnt wait lands AFTER compute
#pragma unroll
      for (int i = 0; i < 12; i++) wbuf[cur ^ 1][woff[i]] = wr[i];
    }
  }

  // epilogue: E = exp(acc + bias), rows rg+32i, cols c0..c0+5
#pragma unroll
  for (int i = 0; i < 4; i++) {
    float* dst = E + (size_t)(rowbase + rg + 32 * i) * L_ + c0;
#pragma unroll
    for (int cc = 0; cc < 6; cc += 2) {
      float2 v;
      v.x = __expf(acc[i][cc + 0] + bias[c0 + cc + 0]);
      v.y = __expf(acc[i][cc + 1] + bias[c0 + cc + 1]);
      *(float2*)(dst + cc) = v;
    }
  }
}

// ---------------------------------------------------------------------------
// Kernel B: one block (128 threads) per batch element; wave 0 = unconstrained
// forward, wave 1 = constrained partial.  Scaled-probability recurrence.
// Round-4 fixes (VGPR=68 revealed spilling; shfl-rescale serialized the
// in-order DS pipe):
//   - __launch_bounds__(128, 1): lifts the VGPR cap (no spills; P[48] +
//     prefetch arrays stay in registers).
//   - prefetch depth 4 (was 8): halves prefetch-array register pressure;
//     4 steps (~1000 cyc) still covers L2/L3 load latency.
//   - rescale with ZERO cross-lane ops: every lane broadcast-reads the full
//     48-value state anyway, so m = max(state) is computed from those reads
//     (elementwise max in the FMA loop + small tree) — uniform across lanes
//     by construction.  1/m folds into the same step's emission multiply.
//     No shuffles, no extra DS ops, no deferred-pend machinery.
//     Cadence: steps t with t%8==1 (max of the state being consumed);
//     worst unscaled stretch <= 11 steps, far inside fp32 range.
// Parity: state(t=0) in parity 0; step i reads i&1, writes (i+1)&1; 4-step
// body keeps bodies starting at parity 0; tail continues from parity 0.
// ---------------------------------------------------------------------------
__global__ __launch_bounds__(128, 1) void crf_scan(
    const float* __restrict__ E, const int* __restrict__ tags,
    const int* __restrict__ lens, const float* __restrict__ begin,
    const float* __restrict__ trans, const float* __restrict__ endt,
    const int* __restrict__ bc, const int* __restrict__ ec,
    const int* __restrict__ tc, float* __restrict__ out) {
  __shared__ __align__(16) float sbuf[2][2][64];  // [wave][parity][slot]
  __shared__ float lzbuf[2];
  const int b = blockIdx.x;
  const int wv = threadIdx.x >> 6;   // 0 = fwd, 1 = constrained partial
  const int lane = threadIdx.x & 63;
  const bool act = lane < L_;
  const bool par = (wv == 1);
  const int len = lens[b];            // in [512, 1024]
  const int stride = B_ * L_;
  const int base = b * L_ + (act ? lane : 0);  // clamped for lanes 48..63

  // Transition row: P[k] = exp(trans[lane][k]); constraint-masked on wave 1.
  float P[L_];
#pragma unroll
  for (int k = 0; k < L_; k++) P[k] = 0.f;
  if (act) {
#pragma unroll
    for (int k = 0; k < L_; k++) {
      float v = __expf(trans[lane * L_ + k]);
      if (par && tc[lane * L_ + k]) v = 0.f;
      P[k] = v;
    }
  }

  // init: a0 = E[0]*exp(begin); wave 1 additionally masked by bc/tags[0]
  float a = 0.f;
  if (act) {
    a = E[base] * __expf(begin[lane]);
    if (par && (bc[lane] || tags[base])) a = 0.f;
  }
  float logacc = 0.f;

  sbuf[wv][0][lane] = a;  // state(t=0) -> parity 0

  // One recurrence step.  resc: divide this step's output by m = max of the
  // input state (read via the same broadcast loads) and log-accumulate m.
  auto step = [&](int i, float ev, int tg, bool resc) {
    const f32x4* src = (const f32x4*)sbuf[wv][i & 1];
    float s0 = 0.f, s1 = 0.f, s2 = 0.f, s3 = 0.f;
    f32x4 mx = {0.f, 0.f, 0.f, 0.f};  // state is non-negative
#pragma unroll
    for (int c = 0; c < 12; c++) {
      const f32x4 q = src[c];
      if (resc) {
        mx.x = fmaxf(mx.x, q.x);
        mx.y = fmaxf(mx.y, q.y);
        mx.z = fmaxf(mx.z, q.z);
        mx.w = fmaxf(mx.w, q.w);
      }
      s0 = fmaf(q.x, P[4 * c + 0], s0);
      s1 = fmaf(q.y, P[4 * c + 1], s1);
      s2 = fmaf(q.z, P[4 * c + 2], s2);
      s3 = fmaf(q.w, P[4 * c + 3], s3);
    }
    float evp = ev;
    if (resc) {
      float m = fmaxf(fmaxf(mx.x, mx.y), fmaxf(mx.z, mx.w));
      m = fmaxf(m, 1e-30f);     // uniform across lanes (same broadcast data)
      logacc += __logf(m);
      evp = ev * (1.f / m);
    }
    float u = ((s0 + s1) + (s2 + s3)) * evp;
    if (tg) u = 0.f;  // tg is always 0 on wave 0
    a = u;
    sbuf[wv][(i + 1) & 1][lane] = u;  // publish for the next step
  };

  // preload emissions/tags for t = 1..4 (len >= 512 so always valid)
  float e4[4];
  int tg4[4];
#pragma unroll
  for (int i = 0; i < 4; i++) {
    e4[i] = E[(size_t)(1 + i) * stride + base];
    tg4[i] = par ? tags[(size_t)(1 + i) * stride + base] : 0;
  }

  int t = 1;  // bodies start at t == 1 (mod 4); rescale when t == 1 (mod 8)
  for (; t + 4 <= len; t += 4) {
    float p4[4];
    int q4[4];
#pragma unroll
    for (int i = 0; i < 4; i++) {
      int tt = t + 4 + i;
      tt = (tt < len) ? tt : (len - 1);
      p4[i] = E[(size_t)tt * stride + base];
      q4[i] = par ? tags[(size_t)tt * stride + base] : 0;
    }
    if ((t & 7) == 1) {
      step(0, e4[0], tg4[0], true);   // specialized resc=true expansion
    } else {
      step(0, e4[0], tg4[0], false);
    }
    step(1, e4[1], tg4[1], false);
    step(2, e4[2], tg4[2], false);
    step(3, e4[3], tg4[3], false);
#pragma unroll
    for (int i = 0; i < 4; i++) { e4[i] = p4[i]; tg4[i] = q4[i]; }
  }
  // tail: at most 3 steps; e4 holds times t..t+3 (clamped); parity continues
#pragma unroll
  for (int i = 0; i < 4; i++) {
    if (t + i < len) step(i, e4[i], tg4[i], false);
  }

  // readout: logZ = logacc + log(sum_j a[j]*exp(end[j]))
  float z = 0.f;
  if (act) {
    float ez = __expf(endt[lane]);
    if (par && ec[lane]) ez = 0.f;
    z = a * ez;
  }
#pragma unroll
  for (int off = 32; off; off >>= 1) z += __shfl_xor(z, off, 64);
  if (lane == 0) lzbuf[wv] = logacc + __logf(z);
  __syncthreads();
  if (threadIdx.x == 0) out[b] = lzbuf[0] - lzbuf[1];
}

// ---------------------------------------------------------------------------
extern "C" void kernel_launch(void* const* d_in, const int* in_sizes, int n_in,
                              void* d_out, int out_size, void* d_ws,
                              size_t ws_size, hipStream_t stream) {
  (void)in_sizes; (void)n_in; (void)out_size; (void)ws_size;
  const float* feats = (const float*)d_in[0];
  const int* tags = (const int*)d_in[1];
  const int* lens = (const int*)d_in[2];
  const float* W = (const float*)d_in[3];
  const float* bias = (const float*)d_in[4];
  const float* begin = (const float*)d_in[5];
  const float* trans = (const float*)d_in[6];
  const float* endt = (const float*)d_in[7];
  const int* bc = (const int*)d_in[8];
  const int* ec = (const int*)d_in[9];
  const int* tc = (const int*)d_in[10];

  float* E = (float*)d_ws;  // T*B*L floats = 6 MB scratch, exp(emissions)
  float* out = (float*)d_out;

  emis_gemm<<<dim3(TB_ / 128), dim3(256), 0, stream>>>(feats, W, bias, E);
  crf_scan<<<dim3(B_), dim3(128), 0, stream>>>(E, tags, lens, begin, trans,
                                               endt, bc, ec, tc, out);
}